// Round 13
// baseline (808.004 us; speedup 1.0000x reference)
//
#include <hip/hip_runtime.h>
#include <math.h>

// 2-layer ReLU RNN, B=256, T=1000 (input 800 + zero pad), H=128, F=5.
// R13: barrier-free pipelined dataflow (protocol validated R9/R12) with each
// matvec engine SPLIT ACROSS 2 WAVES so weights stay in VGPRs (R9/R12 died
// on AGPR parking at 128 weight regs/thread; here 64). 512 thr = 8 waves:
//   wv0/1 E0a/E0b: h0[s] rows 0-63 / 64-127 (in-pair handshake per step)
//   wv2/3 E1a/E1b: A[t] = Wih1.h0[t] + b1
//   wv4/5 E2a/E2b: h1[t] = relu(Whh1.h1[t-1] + A[t])
//   wv6   E3a: xw[t] = Wih0.x[t] (runs ahead);  wv7 E3b: y sigmoids (16/grp)
// Per thread: 8 rows x 16 cols (8 own-half + 8 partner-half cols), 64 fdot2,
// 8-lane all-DPP reduce (0xB1 xor1, 0x4E xor2, 0x141 row_half_mirror).
// Own-half h read prefetched at loop bottom (self-wave DS in-order); partner
// half gated on partner's per-step flag. Flags: monotone counters in LDS;
// publish = compiler-barrier + lane0 ds_write (no fence - same-wave DS
// ordering, validated R12-pass). h1r rows padded to 136 (fixes R12's 646K
// y-path bank conflicts). Ring slacks: h0r/Ar 16 deep, h1r/xwr 32 deep;
// backpressure polls amortized every 4/8 steps; DAG deadlock-free (audit in
// session notes: every blocking wait's producer can always advance).

#define TT    1000
#define TIN   800
#define HD    128
#define HP    136
#define NF    5
#define BATCH 256

typedef float f32x4v __attribute__((ext_vector_type(4)));
typedef _Float16 h16x2 __attribute__((ext_vector_type(2)));
typedef _Float16 h16x8 __attribute__((ext_vector_type(8)));

template<int CTRL>
__device__ __forceinline__ float dpp_mov(float v) {
    union { float f; int i; } u, r;
    u.f = v;
    r.i = __builtin_amdgcn_update_dpp(0, u.i, CTRL, 0xF, 0xF, true);
    return r.f;
}

__device__ __forceinline__ void dots8(const h16x2 (&W)[8][4], h16x8 hv,
                                      float (&acc)[8], bool first) {
    h16x2 p0 = { hv[0], hv[1] }, p1 = { hv[2], hv[3] };
    h16x2 p2 = { hv[4], hv[5] }, p3 = { hv[6], hv[7] };
    #pragma unroll
    for (int j = 0; j < 8; ++j) {
        float a = first ? 0.f : acc[j];
        a = __builtin_amdgcn_fdot2(W[j][0], p0, a, false);
        a = __builtin_amdgcn_fdot2(W[j][1], p1, a, false);
        a = __builtin_amdgcn_fdot2(W[j][2], p2, a, false);
        a = __builtin_amdgcn_fdot2(W[j][3], p3, a, false);
        acc[j] = a;
    }
}
__device__ __forceinline__ void reduce8(float (&acc)[8]) {
    #pragma unroll
    for (int j = 0; j < 8; ++j) acc[j] += dpp_mov<0xB1>(acc[j]);   // xor1
    #pragma unroll
    for (int j = 0; j < 8; ++j) acc[j] += dpp_mov<0x4E>(acc[j]);   // xor2
    #pragma unroll
    for (int j = 0; j < 8; ++j) acc[j] += dpp_mov<0x141>(acc[j]);  // xor4*
}

__global__ __launch_bounds__(512, 1) void rnn_pipe3(
    const float* __restrict__ x,        // [256,800,5]
    const float* __restrict__ h_state,  // [2,256,128]
    const float* __restrict__ w_ih0,    // [128,5]
    const float* __restrict__ w_hh0,    // [128,128]
    const float* __restrict__ b_ih0,    // [128]
    const float* __restrict__ b_hh0,    // [128]
    const float* __restrict__ w_ih1,    // [128,128]
    const float* __restrict__ w_hh1,    // [128,128]
    const float* __restrict__ b_ih1,    // [128]
    const float* __restrict__ b_hh1,    // [128]
    const float* __restrict__ w_out,    // [1,128]
    const float* __restrict__ b_out,    // [1]
    float* __restrict__ out)            // [204800 y] ++ [65536 final states]
{
    __shared__ __align__(16) float     x_lds[TIN * 8];   // 25.6 KB
    __shared__ __align__(16) float     xwr[32][HD];      // 16 KB
    __shared__ __align__(16) _Float16  h0r[16][HD];      // 4 KB
    __shared__ __align__(16) _Float16  h1r[32][HP];      // 8.7 KB (padded)
    __shared__ __align__(16) float     Ar[16][HD];       // 8 KB
    __shared__ float y_lds[TIN];                         // 3.2 KB
    __shared__ int   prog[8];   // 0:E0a 1:E0b 2:E1a 3:E1b 4:E2a 5:E2b 6:y 7:xw

    const int tid = threadIdx.x;
    const int bb  = blockIdx.x;
    const int wv  = tid >> 6;
    const int l   = tid & 63;
    const int rg  = l >> 3;             // row group: 8 rows
    const int cc  = l & 7;              // col chunk: 8 cols per half
    const int rowBase = (wv & 1) * 64;  // for wv<6

    volatile int* vp = prog;
    if (tid < 8) prog[tid] = 0;
    for (int i = tid; i < TIN * NF; i += 512) {
        int t = i / 5, f = i - 5 * t;
        x_lds[t * 8 + f] = x[bb * (TIN * NF) + i];
    }
    if (tid < HD) {
        h0r[15][tid] = (_Float16)h_state[bb * HD + tid];
        h1r[31][tid] = (_Float16)h_state[BATCH * HD + bb * HD + tid];
    }

    // ---- resident weights ----
    h16x2 wA[8][4], wB[8][4];
    float bias[8];
    if (wv < 6) {
        const int eng = wv >> 1;   // 0:hh0 1:ih1 2:hh1
        const float* W = (eng == 0) ? w_hh0 : ((eng == 1) ? w_ih1 : w_hh1);
        const int colA = (eng == 1) ? 0 : rowBase;   // gated flag (eng1: E0a)
        const int colB = colA ^ 64;
        #pragma unroll
        for (int j = 0; j < 8; ++j) {
            const int row = rowBase + rg * 8 + j;
            const float* rp = W + row * HD;
            #pragma unroll
            for (int t = 0; t < 4; ++t) {
                wA[j][t] = (h16x2){ (_Float16)rp[colA + cc * 8 + 2 * t],
                                    (_Float16)rp[colA + cc * 8 + 2 * t + 1] };
                wB[j][t] = (h16x2){ (_Float16)rp[colB + cc * 8 + 2 * t],
                                    (_Float16)rp[colB + cc * 8 + 2 * t + 1] };
            }
            bias[j] = (eng == 0) ? (b_ih0[row] + b_hh0[row])
                    : (eng == 1) ? (b_ih1[row] + b_hh1[row]) : 0.f;
        }
    }
    float w0a[NF], w0b[NF];          // E3a: Wih0 rows l, l+64
    h16x2 woq[16];                   // E3b
    if (wv == 6) {
        #pragma unroll
        for (int f = 0; f < NF; ++f) {
            w0a[f] = w_ih0[l * NF + f];
            w0b[f] = w_ih0[(l + 64) * NF + f];
        }
    } else if (wv == 7) {
        #pragma unroll
        for (int k = 0; k < 16; ++k)
            woq[k] = (h16x2){ (_Float16)w_out[(l & 3) * 32 + 2 * k],
                              (_Float16)w_out[(l & 3) * 32 + 2 * k + 1] };
    }
    const float bout = b_out[0];

    float fin[8];
    #pragma unroll
    for (int j = 0; j < 8; ++j) fin[j] = 0.f;

    __syncthreads();

    #define POLLGE(idx, val, cache) do { if ((cache) < (val)) {            \
        (cache) = vp[idx];                                                 \
        while ((cache) < (val)) { __builtin_amdgcn_s_sleep(1);             \
                                  (cache) = vp[idx]; }                     \
        __asm__ __volatile__("" ::: "memory"); } } while (0)
    #define PUBLISH(idx, val) do { __asm__ __volatile__("" ::: "memory");  \
        if (l == 0) vp[idx] = (val); } while (0)

    if (wv < 2) {
        // ---- E0: h0 recurrence, rows rowBase..rowBase+63 ----
        const int selfF = wv, partF = wv ^ 1;
        int cP = 0, cXW = 0, cb2 = 0, cb3 = 0;
        h16x8 hOwn = *(const h16x8*)&h0r[15][rowBase + cc * 8];
        for (int s = 0; s < TT; ++s) {
            float acc[8];
            dots8(wA, hOwn, acc, true);
            POLLGE(partF, s, cP);
            h16x8 hP = *(const h16x8*)&h0r[(s + 15) & 15][(rowBase ^ 64) + cc * 8];
            dots8(wB, hP, acc, false);
            reduce8(acc);
            if (s < TIN) POLLGE(7, s + 1, cXW);     // wave-uniform
            if (cc == 0) {
                float xw[8];
                if (s < TIN) {
                    f32x4v a = *(const f32x4v*)&xwr[s & 31][rowBase + rg * 8];
                    f32x4v b = *(const f32x4v*)&xwr[s & 31][rowBase + rg * 8 + 4];
                    xw[0]=a[0]; xw[1]=a[1]; xw[2]=a[2]; xw[3]=a[3];
                    xw[4]=b[0]; xw[5]=b[1]; xw[6]=b[2]; xw[7]=b[3];
                } else {
                    #pragma unroll
                    for (int j = 0; j < 8; ++j) xw[j] = 0.f;
                }
                h16x8 pk;
                #pragma unroll
                for (int j = 0; j < 8; ++j) {
                    float v = fmaxf(acc[j] + bias[j] + xw[j], 0.f);
                    pk[j] = (_Float16)v;
                    if (s == TT - 1) fin[j] = v;
                }
                *(h16x8*)&h0r[s & 15][rowBase + rg * 8] = pk;
            }
            if ((s & 3) == 0 && s >= 16) {          // h0r ring bp vs E1
                POLLGE(2, s - 12, cb2); POLLGE(3, s - 12, cb3);
            }
            PUBLISH(selfF, s + 1);
            hOwn = *(const h16x8*)&h0r[s & 15][rowBase + cc * 8];  // prefetch
        }
    } else if (wv < 4) {
        // ---- E1: A[t] = Wih1.h0[t] + b1, rows rowBase.. ----
        const int selfF = wv;
        int c0 = 0, c1 = 0, cb4 = 0, cb5 = 0;
        for (int t = 0; t < TT; ++t) {
            POLLGE(0, t + 1, c0);
            h16x8 hA = *(const h16x8*)&h0r[t & 15][cc * 8];
            float acc[8];
            dots8(wA, hA, acc, true);
            POLLGE(1, t + 1, c1);
            h16x8 hB = *(const h16x8*)&h0r[t & 15][64 + cc * 8];
            dots8(wB, hB, acc, false);
            reduce8(acc);
            if (cc == 0) {
                f32x4v f0 = { acc[0] + bias[0], acc[1] + bias[1],
                              acc[2] + bias[2], acc[3] + bias[3] };
                f32x4v f1 = { acc[4] + bias[4], acc[5] + bias[5],
                              acc[6] + bias[6], acc[7] + bias[7] };
                *(f32x4v*)&Ar[t & 15][rowBase + rg * 8]     = f0;
                *(f32x4v*)&Ar[t & 15][rowBase + rg * 8 + 4] = f1;
            }
            if ((t & 3) == 0 && t >= 16) {          // Ar ring bp vs E2
                POLLGE(4, t - 12, cb4); POLLGE(5, t - 12, cb5);
            }
            PUBLISH(selfF, t + 1);
        }
    } else if (wv < 6) {
        // ---- E2: h1 recurrence, rows rowBase.. ----
        const int selfF = wv, partF = wv ^ 1, aF = wv - 2;
        int cP = 0, cA = 0, c6 = 0;
        h16x8 hOwn = *(const h16x8*)&h1r[31][rowBase + cc * 8];
        for (int t = 0; t < TT; ++t) {
            float acc[8];
            dots8(wA, hOwn, acc, true);
            POLLGE(aF, t + 1, cA);                  // my A half ready
            f32x4v a0 = {0,0,0,0}, a1 = {0,0,0,0};
            if (cc == 0) {
                a0 = *(const f32x4v*)&Ar[t & 15][rowBase + rg * 8];
                a1 = *(const f32x4v*)&Ar[t & 15][rowBase + rg * 8 + 4];
            }
            POLLGE(partF, t, cP);
            h16x8 hP = *(const h16x8*)&h1r[(t + 31) & 31][(rowBase ^ 64) + cc * 8];
            dots8(wB, hP, acc, false);
            reduce8(acc);
            if (cc == 0) {
                h16x8 pk;
                #pragma unroll
                for (int j = 0; j < 8; ++j) {
                    float aj = (j < 4) ? a0[j] : a1[j - 4];
                    float v = fmaxf(acc[j] + aj, 0.f);
                    pk[j] = (_Float16)v;
                    if (t == TT - 1) fin[j] = v;
                }
                *(h16x8*)&h1r[t & 31][rowBase + rg * 8] = pk;
            }
            if ((t & 3) == 0 && t >= 32) {          // h1r ring bp vs y
                int need = t - 28; if (need > TIN) need = TIN;
                POLLGE(6, need, c6);
            }
            PUBLISH(selfF, t + 1);
            hOwn = *(const h16x8*)&h1r[t & 31][rowBase + cc * 8];  // prefetch
        }
    } else if (wv == 6) {
        // ---- E3a: xw[t] = Wih0.x[t], rows l and l+64 ----
        int cb0 = 0, cb1 = 0;
        for (int tt = 0; tt < TIN; ++tt) {
            if (tt >= 32 && (tt & 7) == 0) {        // xwr ring bp vs E0
                POLLGE(0, tt - 24, cb0); POLLGE(1, tt - 24, cb1);
            }
            const float* xr = &x_lds[tt * 8];
            f32x4v xv = *(const f32x4v*)xr;
            float x4 = xr[4];
            float xa = w0a[0]*xv[0] + w0a[1]*xv[1] + w0a[2]*xv[2]
                     + w0a[3]*xv[3] + w0a[4]*x4;
            float xb = w0b[0]*xv[0] + w0b[1]*xv[1] + w0b[2]*xv[2]
                     + w0b[3]*xv[3] + w0b[4]*x4;
            xwr[tt & 31][l]      = xa;
            xwr[tt & 31][l + 64] = xb;
            if ((tt & 3) == 3) PUBLISH(7, tt + 1);
        }
    } else {
        // ---- E3b: y sigmoids, 16 per group, quad-DPP reduce ----
        const int jslot = l >> 2, sub = l & 3;
        int c4 = 0, c5 = 0;
        for (int u0 = 0; u0 < TIN; u0 += 16) {
            POLLGE(4, u0 + 16, c4);
            POLLGE(5, u0 + 16, c5);
            const _Float16* hr = &h1r[(u0 + jslot) & 31][sub * 32];
            h16x8 g0 = *(const h16x8*)(hr);
            h16x8 g1 = *(const h16x8*)(hr + 8);
            h16x8 g2 = *(const h16x8*)(hr + 16);
            h16x8 g3 = *(const h16x8*)(hr + 24);
            float z = 0.f;
            #pragma unroll
            for (int k = 0; k < 4; ++k) {
                z = __builtin_amdgcn_fdot2(woq[k],      (h16x2){ g0[2*k], g0[2*k+1] }, z, false);
                z = __builtin_amdgcn_fdot2(woq[4 + k],  (h16x2){ g1[2*k], g1[2*k+1] }, z, false);
                z = __builtin_amdgcn_fdot2(woq[8 + k],  (h16x2){ g2[2*k], g2[2*k+1] }, z, false);
                z = __builtin_amdgcn_fdot2(woq[12 + k], (h16x2){ g3[2*k], g3[2*k+1] }, z, false);
            }
            z += dpp_mov<0xB1>(z);
            z += dpp_mov<0x4E>(z);
            if (sub == 0) y_lds[u0 + jslot] = 1.f / (1.f + expf(-(z + bout)));
            PUBLISH(6, u0 + 16);
        }
    }

    __syncthreads();

    // ---- epilogue: single global dump ----
    for (int i = tid; i < TIN; i += 512)
        out[bb * TIN + i] = y_lds[i];
    if (wv < 2 && cc == 0) {
        #pragma unroll
        for (int j = 0; j < 8; ++j)
            out[TIN * BATCH + bb * HD + rowBase + rg * 8 + j] = fin[j];
    }
    if ((wv == 4 || wv == 5) && cc == 0) {
        #pragma unroll
        for (int j = 0; j < 8; ++j)
            out[TIN * BATCH + BATCH * HD + bb * HD + rowBase + rg * 8 + j] = fin[j];
    }
}

extern "C" void kernel_launch(void* const* d_in, const int* in_sizes, int n_in,
                              void* d_out, int out_size, void* d_ws, size_t ws_size,
                              hipStream_t stream) {
    (void)in_sizes; (void)n_in; (void)d_ws; (void)ws_size; (void)out_size;
    rnn_pipe3<<<dim3(BATCH), dim3(512), 0, stream>>>(
        (const float*)d_in[0],  (const float*)d_in[1],
        (const float*)d_in[2],  (const float*)d_in[3],
        (const float*)d_in[4],  (const float*)d_in[5],
        (const float*)d_in[6],  (const float*)d_in[7],
        (const float*)d_in[8],  (const float*)d_in[9],
        (const float*)d_in[10], (const float*)d_in[11],
        (float*)d_out);
}

// Round 14
// 510.804 us; speedup vs baseline: 1.5818x; 1.5818x over previous
//
#include <hip/hip_runtime.h>
#include <math.h>

// 2-layer ReLU RNN, B=256, T=1000 (input 800 + zero pad), H=128, F=5.
// R14 = R10 (best: 508us total / 467 best-dispatch) + x register prefetch.
// R10 skeleton (verified): 768 thr = 3 matvec groups x 256, 8x8 tiles,
// XOR-linear row map, all-DPP 16-lane reduce, fdot2, ONE barrier/step,
// y-dots every 16 steps DPP-only, no global ops in the loop.
// R14 change: g0's x-term operand is prefetched into registers at the
// BOTTOM of step s for step s+1 (x is static) -> its ~120cyc DS latency
// hides under the barrier wait, and the post-barrier DS burst loses one
// b128 per g0 wave. Post-barrier g0 chain is now a single dependent read.
// Barrier-free variants (R9/R12/R13: 668/609/808us) all lost to this
// skeleton: LDS flag round-trips >= barrier cost; weights cap at ~64
// VGPR/thread before AGPR parking, forcing >=2 waves per matvec.

#define TT    1000
#define TIN   800
#define HD    128
#define NF    5
#define BATCH 256

typedef _Float16 h16x2 __attribute__((ext_vector_type(2)));
typedef _Float16 h16x8 __attribute__((ext_vector_type(8)));

template<int CTRL>
__device__ __forceinline__ float dpp_mov(float v) {
    union { float f; int i; } u, r;
    u.f = v;
    r.i = __builtin_amdgcn_update_dpp(0, u.i, CTRL, 0xF, 0xF, true);
    return r.f;
}

__global__ __launch_bounds__(768, 3) void rnn_dot2(
    const float* __restrict__ x,        // [256,800,5]
    const float* __restrict__ h_state,  // [2,256,128]
    const float* __restrict__ w_ih0,    // [128,5]
    const float* __restrict__ w_hh0,    // [128,128]
    const float* __restrict__ b_ih0,    // [128]
    const float* __restrict__ b_hh0,    // [128]
    const float* __restrict__ w_ih1,    // [128,128]
    const float* __restrict__ w_hh1,    // [128,128]
    const float* __restrict__ b_ih1,    // [128]
    const float* __restrict__ b_hh1,    // [128]
    const float* __restrict__ w_out,    // [1,128]
    const float* __restrict__ b_out,    // [1]
    float* __restrict__ out)            // [204800 y] ++ [65536 final states]
{
    __shared__ __align__(16) _Float16 x_h[TIN * 8];      // fp16, 12.8 KB
    __shared__ __align__(16) _Float16 h0h[2][HD];
    __shared__ __align__(16) _Float16 h1h[2][HD];
    __shared__ float A_f[2][HD];                         // fp32 pre-act
    __shared__ __align__(16) _Float16 ring[32][HD];      // h1 history, 8 KB
    __shared__ float y_lds[TIN];                         // 3.2 KB

    const int tid = threadIdx.x;
    const int bb  = blockIdx.x;         // batch element
    const int grp = tid >> 8;           // 0,1,2 : matvec engine
    const int lt  = tid & 255;
    const int c   = lt & 15;            // col chunk / reduction lane
    const int rg  = lt >> 4;            // row group (8 rows)
    const int g   = (4 * (c & 1)) ^ (2 * ((c >> 1) & 1)) ^ (7 * ((c >> 2) & 1));
    const int row = rg * 8 + g;         // row this thread finalizes
    const bool writer = (c & 8) == 0;

    // ---- stage x[bb] into LDS (fp16, stride 8, pads zero) ----
    for (int i = tid; i < TIN * 8; i += 768) x_h[i] = (_Float16)0.f;
    __syncthreads();
    for (int i = tid; i < TIN * NF; i += 768) {
        int t = i / 5, f = i - 5 * t;
        x_h[t * 8 + f] = (_Float16)x[bb * (TIN * NF) + i];
    }
    if (tid < HD) {
        h0h[0][tid] = (_Float16)h_state[bb * HD + tid];
        h1h[0][tid] = (_Float16)h_state[BATCH * HD + bb * HD + tid];
    }

    // ---- weights: my 8x8 tile, rows rg*8+(j^g), cols c*8..c*8+7, fp16 ----
    const float* Wsrc = (grp == 0) ? w_hh0 : ((grp == 1) ? w_ih1 : w_hh1);
    h16x2 wp[8][4];
    #pragma unroll
    for (int j = 0; j < 8; ++j) {
        const float* rp = Wsrc + (rg * 8 + (j ^ g)) * HD + c * 8;
        #pragma unroll
        for (int t = 0; t < 4; ++t) {
            h16x2 w2 = { (_Float16)rp[2 * t], (_Float16)rp[2 * t + 1] };
            wp[j][t] = w2;
        }
    }
    h16x2 wx0 = {0,0}, wx1 = {0,0}, wx2 = {0,0};   // g0: Wih0 row (fp16)
    h16x2 wo[4];                                    // g1: wout[l4*8..+7]
    float bias = 0.f;
    if (grp == 0) {
        wx0[0] = (_Float16)w_ih0[row * NF + 0];
        wx0[1] = (_Float16)w_ih0[row * NF + 1];
        wx1[0] = (_Float16)w_ih0[row * NF + 2];
        wx1[1] = (_Float16)w_ih0[row * NF + 3];
        wx2[0] = (_Float16)w_ih0[row * NF + 4];
        bias = b_ih0[row] + b_hh0[row];
    } else if (grp == 1) {
        const int l4 = lt & 15;
        #pragma unroll
        for (int t = 0; t < 4; ++t) {
            wo[t][0] = (_Float16)w_out[l4 * 8 + 2 * t];
            wo[t][1] = (_Float16)w_out[l4 * 8 + 2 * t + 1];
        }
        bias = 0.f;
    } else {
        bias = b_ih1[row] + b_hh1[row];
    }
    const float bout = b_out[0];

    float hfin = 0.f;   // grp0 writer: h0[999]; grp2 writer: h1[999]

    __syncthreads();

    // 8x8 tile matvec via fdot2 + all-DPP 16-lane reduction (R2/R7-verified).
    auto matvec = [&](const _Float16* hbuf) -> float {
        h16x8 hv = *(const h16x8*)(hbuf + c * 8);
        h16x2 hp0 = { hv[0], hv[1] }, hp1 = { hv[2], hv[3] };
        h16x2 hp2 = { hv[4], hv[5] }, hp3 = { hv[6], hv[7] };
        float a[8];
        #pragma unroll
        for (int j = 0; j < 8; ++j) {
            float aj;
            aj = __builtin_amdgcn_fdot2(wp[j][0], hp0, 0.f, false);
            aj = __builtin_amdgcn_fdot2(wp[j][1], hp1, aj,  false);
            aj = __builtin_amdgcn_fdot2(wp[j][2], hp2, aj,  false);
            aj = __builtin_amdgcn_fdot2(wp[j][3], hp3, aj,  false);
            a[j] = aj;
        }
        a[0] += dpp_mov<0xB1>(a[4]);   // xor1
        a[1] += dpp_mov<0xB1>(a[5]);
        a[2] += dpp_mov<0xB1>(a[6]);
        a[3] += dpp_mov<0xB1>(a[7]);
        a[0] += dpp_mov<0x4E>(a[2]);   // xor2
        a[1] += dpp_mov<0x4E>(a[3]);
        a[0] += dpp_mov<0x140>(a[1]);  // xor15 (row_mirror)
        a[0] += dpp_mov<0x128>(a[0]);  // xor8  (row_ror:8)
        return a[0];
    };

    // g0: x operand for step s held in registers, prefetched one step ahead
    h16x8 xv = {};
    if (grp == 0) xv = *(const h16x8*)(&x_h[0]);

    #pragma unroll 2
    for (int s = 0; s < TT + 2; ++s) {
        const int p = s & 1;
        const int q = p ^ 1;

        if (grp == 0) {
            // h0[s] = relu(Whh0.h0[s-1] + Wih0.x[s] + b)
            if (s < TT) {
                float acc = matvec(h0h[p]);
                float v = acc + bias;
                if (s < TIN) {
                    h16x2 xp0 = { xv[0], xv[1] }, xp1 = { xv[2], xv[3] };
                    h16x2 xp2 = { xv[4], xv[5] };
                    float xc = __builtin_amdgcn_fdot2(wx2, xp2, 0.f, false);
                    xc = __builtin_amdgcn_fdot2(wx1, xp1, xc, false);
                    xc = __builtin_amdgcn_fdot2(wx0, xp0, xc, false);
                    v += xc;
                }
                v = fmaxf(v, 0.f);
                if (writer) {
                    h0h[q][row] = (_Float16)v;
                    if (s == TT - 1) hfin = v;
                }
            }
            // prefetch x for step s+1 (static data; latency hides in barrier)
            {
                const int nxt = (s + 1 < TIN) ? (s + 1) * 8 : 0;
                xv = *(const h16x8*)(&x_h[nxt]);
            }
        } else if (grp == 1) {
            // A[s-1] = Wih1 . h0[s-1]  (fp32)
            if (s <= TT) {
                float acc = matvec(h0h[p]);
                if (writer) A_f[q][row] = acc;
            }
            // y-dots every 16 steps: 16 slots x 16 lanes, DPP-only reduce
            if (s >= 18 && s <= 818 && ((s - 2) & 15) == 0) {
                const int u  = (s - 33) + (lt >> 4);   // slot = lt>>4
                const int l4 = lt & 15;
                if (u >= 0 && u < TIN) {
                    h16x8 hv = *(const h16x8*)(&ring[u & 31][l4 * 8]);
                    h16x2 hp0 = { hv[0], hv[1] }, hp1 = { hv[2], hv[3] };
                    h16x2 hp2 = { hv[4], hv[5] }, hp3 = { hv[6], hv[7] };
                    float z;
                    z = __builtin_amdgcn_fdot2(wo[0], hp0, 0.f, false);
                    z = __builtin_amdgcn_fdot2(wo[1], hp1, z,  false);
                    z = __builtin_amdgcn_fdot2(wo[2], hp2, z,  false);
                    z = __builtin_amdgcn_fdot2(wo[3], hp3, z,  false);
                    z += dpp_mov<0xB1>(z);    // xor1
                    z += dpp_mov<0x4E>(z);    // xor2
                    z += dpp_mov<0x140>(z);   // xor15
                    z += dpp_mov<0x128>(z);   // xor8
                    if (l4 == 0) y_lds[u] = 1.f / (1.f + expf(-(z + bout)));
                }
            }
        } else {
            // h1[s-2] = relu(A[s-2] + Whh1.h1[s-3] + b)
            if (s >= 2) {
                const int u = s - 2;
                float acc = matvec(h1h[p]);
                float v = fmaxf(acc + bias + A_f[p][row], 0.f);
                if (writer) {
                    _Float16 vh = (_Float16)v;
                    h1h[q][row] = vh;
                    if (u < TIN) ring[u & 31][row] = vh;
                    if (u == TT - 1) hfin = v;
                }
            }
        }
        __syncthreads();
    }

    // ---- epilogue: single global dump ----
    for (int i = tid; i < TIN; i += 768)
        out[bb * TIN + i] = y_lds[i];
    if (grp == 0 && writer)
        out[TIN * BATCH + bb * HD + row] = hfin;
    if (grp == 2 && writer)
        out[TIN * BATCH + BATCH * HD + bb * HD + row] = hfin;
}

extern "C" void kernel_launch(void* const* d_in, const int* in_sizes, int n_in,
                              void* d_out, int out_size, void* d_ws, size_t ws_size,
                              hipStream_t stream) {
    (void)in_sizes; (void)n_in; (void)d_ws; (void)ws_size; (void)out_size;
    rnn_dot2<<<dim3(BATCH), dim3(768), 0, stream>>>(
        (const float*)d_in[0],  (const float*)d_in[1],
        (const float*)d_in[2],  (const float*)d_in[3],
        (const float*)d_in[4],  (const float*)d_in[5],
        (const float*)d_in[6],  (const float*)d_in[7],
        (const float*)d_in[8],  (const float*)d_in[9],
        (const float*)d_in[10], (const float*)d_in[11],
        (float*)d_out);
}

// Round 15
// 504.163 us; speedup vs baseline: 1.6027x; 1.0132x over previous
//
#include <hip/hip_runtime.h>
#include <math.h>

// 2-layer ReLU RNN, B=256, T=1000 (input 800 + zero pad), H=128, F=5.
// R15 = R10 (best skeleton: 768 thr = 3 matvec groups x 256, 8x8 tiles,
// XOR-linear row map, all-DPP 16-lane reduce, fdot2, ONE barrier/step,
// y-dots every 16 steps DPP-only, no global ops in loop) + DS-burst trims:
//  - h1 state unified into the depth-32 ring (read h1[t-1] from
//    ring[(t-1)&31]); removes one u16 write/writer/step. Slot-reuse audit:
//    slot u&31 overwritten at u+32; y consumer reads u at s<=u+33<=u+48 but
//    always >=16 steps before overwrite (verified offsets).
//  - A_f read (g2) and x read+dots (g0) exec-masked to writer lanes:
//    non-writer values are dead (DPP reduce gives writers the full sum);
//    halves those post-barrier DS bursts.
//  - R14's x prefetch reverted (measured neutral-negative).
// History: MFMA (R3-R6) capped by 16x broadcast waste; barrier-free flags
// (R9/R12/R13) lose to the barrier (LDS poll >= barrier cost); merges/
// splits/batching (R8/R11/R13) lengthen the serial path. This skeleton's
// step = ~1120 cyc: ~350 issue + DS bursts + 12-wave convoy + barrier.

#define TT    1000
#define TIN   800
#define HD    128
#define NF    5
#define BATCH 256

typedef _Float16 h16x2 __attribute__((ext_vector_type(2)));
typedef _Float16 h16x8 __attribute__((ext_vector_type(8)));

template<int CTRL>
__device__ __forceinline__ float dpp_mov(float v) {
    union { float f; int i; } u, r;
    u.f = v;
    r.i = __builtin_amdgcn_update_dpp(0, u.i, CTRL, 0xF, 0xF, true);
    return r.f;
}

__global__ __launch_bounds__(768, 3) void rnn_dot2(
    const float* __restrict__ x,        // [256,800,5]
    const float* __restrict__ h_state,  // [2,256,128]
    const float* __restrict__ w_ih0,    // [128,5]
    const float* __restrict__ w_hh0,    // [128,128]
    const float* __restrict__ b_ih0,    // [128]
    const float* __restrict__ b_hh0,    // [128]
    const float* __restrict__ w_ih1,    // [128,128]
    const float* __restrict__ w_hh1,    // [128,128]
    const float* __restrict__ b_ih1,    // [128]
    const float* __restrict__ b_hh1,    // [128]
    const float* __restrict__ w_out,    // [1,128]
    const float* __restrict__ b_out,    // [1]
    float* __restrict__ out)            // [204800 y] ++ [65536 final states]
{
    __shared__ __align__(16) _Float16 x_h[TIN * 8];      // fp16, 12.8 KB
    __shared__ __align__(16) _Float16 h0h[2][HD];
    __shared__ float A_f[2][HD];                         // fp32 pre-act
    __shared__ __align__(16) _Float16 ring[32][HD];      // h1 state+history
    __shared__ float y_lds[TIN];                         // 3.2 KB

    const int tid = threadIdx.x;
    const int bb  = blockIdx.x;         // batch element
    const int grp = tid >> 8;           // 0,1,2 : matvec engine
    const int lt  = tid & 255;
    const int c   = lt & 15;            // col chunk / reduction lane
    const int rg  = lt >> 4;            // row group (8 rows)
    const int g   = (4 * (c & 1)) ^ (2 * ((c >> 1) & 1)) ^ (7 * ((c >> 2) & 1));
    const int row = rg * 8 + g;         // row this thread finalizes
    const bool writer = (c & 8) == 0;

    // ---- stage x[bb] into LDS (fp16, stride 8, pads zero) ----
    for (int i = tid; i < TIN * 8; i += 768) x_h[i] = (_Float16)0.f;
    __syncthreads();
    for (int i = tid; i < TIN * NF; i += 768) {
        int t = i / 5, f = i - 5 * t;
        x_h[t * 8 + f] = (_Float16)x[bb * (TIN * NF) + i];
    }
    if (tid < HD) {
        h0h[0][tid]  = (_Float16)h_state[bb * HD + tid];
        ring[31][tid] = (_Float16)h_state[BATCH * HD + bb * HD + tid];  // h1[-1]
    }

    // ---- weights: my 8x8 tile, rows rg*8+(j^g), cols c*8..c*8+7, fp16 ----
    const float* Wsrc = (grp == 0) ? w_hh0 : ((grp == 1) ? w_ih1 : w_hh1);
    h16x2 wp[8][4];
    #pragma unroll
    for (int j = 0; j < 8; ++j) {
        const float* rp = Wsrc + (rg * 8 + (j ^ g)) * HD + c * 8;
        #pragma unroll
        for (int t = 0; t < 4; ++t) {
            h16x2 w2 = { (_Float16)rp[2 * t], (_Float16)rp[2 * t + 1] };
            wp[j][t] = w2;
        }
    }
    h16x2 wx0 = {0,0}, wx1 = {0,0}, wx2 = {0,0};   // g0: Wih0 row (fp16)
    h16x2 wo[4];                                    // g1: wout[l4*8..+7]
    float bias = 0.f;
    if (grp == 0) {
        wx0[0] = (_Float16)w_ih0[row * NF + 0];
        wx0[1] = (_Float16)w_ih0[row * NF + 1];
        wx1[0] = (_Float16)w_ih0[row * NF + 2];
        wx1[1] = (_Float16)w_ih0[row * NF + 3];
        wx2[0] = (_Float16)w_ih0[row * NF + 4];
        bias = b_ih0[row] + b_hh0[row];
    } else if (grp == 1) {
        const int l4 = lt & 15;
        #pragma unroll
        for (int t = 0; t < 4; ++t) {
            wo[t][0] = (_Float16)w_out[l4 * 8 + 2 * t];
            wo[t][1] = (_Float16)w_out[l4 * 8 + 2 * t + 1];
        }
        bias = 0.f;
    } else {
        bias = b_ih1[row] + b_hh1[row];
    }
    const float bout = b_out[0];

    float hfin = 0.f;   // grp0 writer: h0[999]; grp2 writer: h1[999]

    __syncthreads();

    // 8x8 tile matvec via fdot2 + all-DPP 16-lane reduction (R2/R7-verified).
    auto matvec = [&](const _Float16* hbuf) -> float {
        h16x8 hv = *(const h16x8*)(hbuf + c * 8);
        h16x2 hp0 = { hv[0], hv[1] }, hp1 = { hv[2], hv[3] };
        h16x2 hp2 = { hv[4], hv[5] }, hp3 = { hv[6], hv[7] };
        float a[8];
        #pragma unroll
        for (int j = 0; j < 8; ++j) {
            float aj;
            aj = __builtin_amdgcn_fdot2(wp[j][0], hp0, 0.f, false);
            aj = __builtin_amdgcn_fdot2(wp[j][1], hp1, aj,  false);
            aj = __builtin_amdgcn_fdot2(wp[j][2], hp2, aj,  false);
            aj = __builtin_amdgcn_fdot2(wp[j][3], hp3, aj,  false);
            a[j] = aj;
        }
        a[0] += dpp_mov<0xB1>(a[4]);   // xor1
        a[1] += dpp_mov<0xB1>(a[5]);
        a[2] += dpp_mov<0xB1>(a[6]);
        a[3] += dpp_mov<0xB1>(a[7]);
        a[0] += dpp_mov<0x4E>(a[2]);   // xor2
        a[1] += dpp_mov<0x4E>(a[3]);
        a[0] += dpp_mov<0x140>(a[1]);  // xor15 (row_mirror)
        a[0] += dpp_mov<0x128>(a[0]);  // xor8  (row_ror:8)
        return a[0];
    };

    #pragma unroll 2
    for (int s = 0; s < TT + 2; ++s) {
        const int p = s & 1;
        const int q = p ^ 1;

        if (grp == 0) {
            // h0[s] = relu(Whh0.h0[s-1] + Wih0.x[s] + b)
            if (s < TT) {
                float acc = matvec(h0h[p]);
                float v = acc + bias;
                if (writer && s < TIN) {   // masked: non-writer v is dead
                    h16x8 xv = *(const h16x8*)(&x_h[s * 8]);
                    h16x2 xp0 = { xv[0], xv[1] }, xp1 = { xv[2], xv[3] };
                    h16x2 xp2 = { xv[4], xv[5] };
                    float xc = __builtin_amdgcn_fdot2(wx2, xp2, 0.f, false);
                    xc = __builtin_amdgcn_fdot2(wx1, xp1, xc, false);
                    xc = __builtin_amdgcn_fdot2(wx0, xp0, xc, false);
                    v += xc;
                }
                v = fmaxf(v, 0.f);
                if (writer) {
                    h0h[q][row] = (_Float16)v;
                    if (s == TT - 1) hfin = v;
                }
            }
        } else if (grp == 1) {
            // A[s-1] = Wih1 . h0[s-1]  (fp32)
            if (s <= TT) {
                float acc = matvec(h0h[p]);
                if (writer) A_f[q][row] = acc;
            }
            // y-dots every 16 steps: 16 slots x 16 lanes, DPP-only reduce
            if (s >= 18 && s <= 818 && ((s - 2) & 15) == 0) {
                const int u  = (s - 33) + (lt >> 4);   // slot = lt>>4
                const int l4 = lt & 15;
                if (u >= 0 && u < TIN) {
                    h16x8 hv = *(const h16x8*)(&ring[u & 31][l4 * 8]);
                    h16x2 hp0 = { hv[0], hv[1] }, hp1 = { hv[2], hv[3] };
                    h16x2 hp2 = { hv[4], hv[5] }, hp3 = { hv[6], hv[7] };
                    float z;
                    z = __builtin_amdgcn_fdot2(wo[0], hp0, 0.f, false);
                    z = __builtin_amdgcn_fdot2(wo[1], hp1, z,  false);
                    z = __builtin_amdgcn_fdot2(wo[2], hp2, z,  false);
                    z = __builtin_amdgcn_fdot2(wo[3], hp3, z,  false);
                    z += dpp_mov<0xB1>(z);    // xor1
                    z += dpp_mov<0x4E>(z);    // xor2
                    z += dpp_mov<0x140>(z);   // xor15
                    z += dpp_mov<0x128>(z);   // xor8
                    if (l4 == 0) y_lds[u] = 1.f / (1.f + expf(-(z + bout)));
                }
            }
        } else {
            // h1[s-2] = relu(A[s-2] + Whh1.h1[s-3] + b); h1 lives in ring
            if (s >= 2) {
                const int u = s - 2;
                float acc = matvec(ring[(u + 31) & 31]);   // h1[u-1]
                float pre = 0.f;
                if (writer) pre = A_f[p][row];             // masked read
                float v = fmaxf(acc + bias + pre, 0.f);
                if (writer) {
                    ring[u & 31][row] = (_Float16)v;       // state + history
                    if (u == TT - 1) hfin = v;
                }
            }
        }
        __syncthreads();
    }

    // ---- epilogue: single global dump ----
    for (int i = tid; i < TIN; i += 768)
        out[bb * TIN + i] = y_lds[i];
    if (grp == 0 && writer)
        out[TIN * BATCH + bb * HD + row] = hfin;
    if (grp == 2 && writer)
        out[TIN * BATCH + BATCH * HD + bb * HD + row] = hfin;
}

extern "C" void kernel_launch(void* const* d_in, const int* in_sizes, int n_in,
                              void* d_out, int out_size, void* d_ws, size_t ws_size,
                              hipStream_t stream) {
    (void)in_sizes; (void)n_in; (void)d_ws; (void)ws_size; (void)out_size;
    rnn_dot2<<<dim3(BATCH), dim3(768), 0, stream>>>(
        (const float*)d_in[0],  (const float*)d_in[1],
        (const float*)d_in[2],  (const float*)d_in[3],
        (const float*)d_in[4],  (const float*)d_in[5],
        (const float*)d_in[6],  (const float*)d_in[7],
        (const float*)d_in[8],  (const float*)d_in[9],
        (const float*)d_in[10], (const float*)d_in[11],
        (float*)d_out);
}